// Round 13
// baseline (202.160 us; speedup 1.0000x reference)
//
#include <hip/hip_runtime.h>

using f16 = _Float16;
typedef _Float16 f16x8 __attribute__((ext_vector_type(8)));
typedef _Float16 f16x4 __attribute__((ext_vector_type(4)));
typedef float f32x4 __attribute__((ext_vector_type(4)));
typedef float f32x16 __attribute__((ext_vector_type(16)));
typedef uint32_t u32;
typedef unsigned int u32x4 __attribute__((ext_vector_type(4)));
typedef __fp16 h16x2 __attribute__((ext_vector_type(2)));

constexpr int DIMC   = 1024;
constexpr int NSEQ   = 2048;
constexpr int NKV    = 2112;   // 2048 + 64 memories = 33 chunks of 64
constexpr int NCHUNK = 33;
constexpr int NBATCH = 4;

__device__ __forceinline__ int swz8(int row, int slot) { return slot ^ (row & 7); }

__device__ __forceinline__ u32 pkrtz(float a, float b) {
    h16x2 t = __builtin_amdgcn_cvt_pkrtz(a, b);
    return __builtin_bit_cast(u32, t);
}

// async 16B global -> LDS (linear dest = wave-uniform base + lane*16)
__device__ __forceinline__ void gld16(const f16* g, f16* l) {
    __builtin_amdgcn_global_load_lds(
        (const __attribute__((address_space(1))) u32*)g,
        (__attribute__((address_space(3))) u32*)l,
        16, 0, 0);
}

// ---------------- LayerNorm fp32 -> fp16 ----------------
__global__ __launch_bounds__(256)
void ln_kernel(const float* __restrict__ x, const float* __restrict__ gamma,
               const float* __restrict__ beta, f16* __restrict__ xn)
{
    const int row = blockIdx.x;
    const int tid = threadIdx.x;
    const float4 v = *reinterpret_cast<const float4*>(x + (size_t)row * DIMC + tid * 4);
    float s  = v.x + v.y + v.z + v.w;
    float ss = v.x*v.x + v.y*v.y + v.z*v.z + v.w*v.w;
#pragma unroll
    for (int off = 1; off < 64; off <<= 1) {
        s  += __shfl_xor(s,  off, 64);
        ss += __shfl_xor(ss, off, 64);
    }
    __shared__ float ps[4], pss[4];
    const int w = tid >> 6;
    if ((tid & 63) == 0) { ps[w] = s; pss[w] = ss; }
    __syncthreads();
    s  = ps[0]  + ps[1]  + ps[2]  + ps[3];
    ss = pss[0] + pss[1] + pss[2] + pss[3];
    const float mu   = s * (1.0f / 1024.0f);
    const float var  = ss * (1.0f / 1024.0f) - mu * mu;
    const float rstd = rsqrtf(var + 1e-5f);
    const float4 gv = *reinterpret_cast<const float4*>(gamma + tid * 4);
    const float4 bv = *reinterpret_cast<const float4*>(beta  + tid * 4);
    f16x4 o;
    o[0] = (f16)((v.x - mu) * rstd * gv.x + bv.x);
    o[1] = (f16)((v.y - mu) * rstd * gv.y + bv.y);
    o[2] = (f16)((v.z - mu) * rstd * gv.z + bv.z);
    o[3] = (f16)((v.w - mu) * rstd * gv.w + bv.w);
    *reinterpret_cast<f16x4*>(xn + (size_t)row * DIMC + tid * 4) = o;
}

// ---------------- fused weight transpose+cast + memories cast ----------------
__device__ __forceinline__ void transpose_tile(
    const float* __restrict__ in, f16* __restrict__ out,
    int R, int C, float scale, int bx, int by)
{
    __shared__ float tile[32][33];
    const int c0 = bx * 32;
    const int r0 = by * 32;
    const int tx = threadIdx.x;       // 0..31
    const int ty = threadIdx.y;       // 0..7
#pragma unroll
    for (int i = 0; i < 4; ++i)
        tile[ty + i * 8][tx] = in[(size_t)(r0 + ty + i * 8) * C + c0 + tx];
    __syncthreads();
#pragma unroll
    for (int i = 0; i < 4; ++i)
        out[(size_t)(c0 + ty + i * 8) * R + r0 + tx] = (f16)(tile[tx][ty + i * 8] * scale);
}

__global__ __launch_bounds__(256)
void prep_kernel(const float* __restrict__ Wq, const float* __restrict__ Wkv,
                 const float* __restrict__ Wo, const float* __restrict__ mem,
                 f16* __restrict__ wqT, f16* __restrict__ wkvT,
                 f16* __restrict__ woT, f16* __restrict__ mem16)
{
    const int bx = blockIdx.x, by = blockIdx.y;
    if (by < 32) {
        if (bx < 32) transpose_tile(Wq, wqT, 1024, 1024, 0.125f * 1.44269504088896341f, bx, by);
    } else if (by < 64) {
        transpose_tile(Wkv, wkvT, 1024, 2048, 1.0f, bx, by - 32);
    } else if (by < 96) {
        if (bx < 32) transpose_tile(Wo, woT, 1024, 1024, 1.0f, bx, by - 64);
    } else {
        const int tid = threadIdx.y * 32 + threadIdx.x;
        const int i = bx * 256 + tid;
        const float4 v = *reinterpret_cast<const float4*>(mem + (size_t)i * 4);
        f16x4 o; o[0] = (f16)v.x; o[1] = (f16)v.y; o[2] = (f16)v.z; o[3] = (f16)v.w;
        *reinterpret_cast<f16x4*>(mem16 + (size_t)i * 4) = o;
    }
}

// ---------------- MFMA GEMM body, 128² tile + counted-vmcnt double-buffer ------
// As/Bs are 2-slot (2 x 128 x 64 f16 each = 32 KB each, 64 KB total -> 2 blocks/CU).
// Schedule per K-tile kt (validated pattern from attn r8):
//   stage(kt+1) -> slot (kt+1)&1   [issued BEFORE the wait; overlaps latency]
//   s_waitcnt vmcnt(8)             [stage(kt) drained; stage(kt+1)'s 8 in flight]
//   s_barrier                      [all waves' stage(kt) complete]
//   compute(kt) from slot kt&1
//   s_barrier                      [slot free for overwrite next iteration]
// MODE 0: q proj -> head-major [b][h][n][64]
// MODE 1: kv proj -> K head-major [b][h][kv][64]; V chunk-tiled [b][h][33][64d][64kv]
// MODE 2: out proj -> fp32 + bias, natural layout
template<int MODE>
__device__ __forceinline__ void gemm_body(
    int tm, int tn, f16* As, f16* Bs,
    const f16* __restrict__ A, const f16* __restrict__ BT,
    const f16* __restrict__ mem16,
    f16* __restrict__ Cf16, f16* __restrict__ Vt,
    float* __restrict__ Cf32, const float* __restrict__ bias)
{
    const int tid = threadIdx.x;
    const int lane = tid & 63, w = tid >> 6;
    const int wm = (w >> 1) * 64, wn = (w & 1) * 64;
    const int l3 = lane >> 3, l7 = lane & 7;
    const int gslot = (l7 ^ l3) * 8;          // pre-swizzled k-offset (elems)

    f32x4 acc[4][4] = {};

    const f16* ag[4];
    const f16* bg[4];
#pragma unroll
    for (int i = 0; i < 4; ++i) {
        const int rl = w * 32 + i * 8 + l3;
        const int gm = tm * 128 + rl;
        if (MODE == 1) {
            const int bb = gm / NKV;
            const int rr = gm - bb * NKV;
            ag[i] = ((rr < NSEQ) ? (A + ((size_t)bb * NSEQ + rr) * DIMC)
                                 : (mem16 + (size_t)(rr - NSEQ) * DIMC)) + gslot;
        } else {
            ag[i] = A + (size_t)gm * DIMC + gslot;
        }
        bg[i] = BT + (size_t)(tn * 128 + rl) * DIMC + gslot;
    }

    auto stage = [&](int kt) {
        const int so = (kt & 1) * 8192;
        const int kb = kt * 64;
#pragma unroll
        for (int i = 0; i < 4; ++i) {
            gld16(ag[i] + kb, &As[so + (w * 32 + i * 8) * 64]);
            gld16(bg[i] + kb, &Bs[so + (w * 32 + i * 8) * 64]);
        }
    };

    stage(0);
    for (int kt = 0; kt < 16; ++kt) {
        if (kt + 1 < 16) {
            stage(kt + 1);
            asm volatile("s_waitcnt vmcnt(8)" ::: "memory");
        } else {
            asm volatile("s_waitcnt vmcnt(0)" ::: "memory");
        }
        __builtin_amdgcn_s_barrier();

        const f16* Asl = &As[(kt & 1) * 8192];
        const f16* Bsl = &Bs[(kt & 1) * 8192];
#pragma unroll
        for (int kk = 0; kk < 2; ++kk) {
            f16x8 af[4], bf[4];
            const int rsel  = lane & 15;
            const int slot0 = (lane >> 4) + kk * 4;
#pragma unroll
            for (int mi = 0; mi < 4; ++mi) {
                const int row = wm + mi * 16 + rsel;
                af[mi] = *reinterpret_cast<const f16x8*>(&Asl[row * 64 + swz8(row, slot0) * 8]);
            }
#pragma unroll
            for (int nj = 0; nj < 4; ++nj) {
                const int row = wn + nj * 16 + rsel;
                bf[nj] = *reinterpret_cast<const f16x8*>(&Bsl[row * 64 + swz8(row, slot0) * 8]);
            }
            __builtin_amdgcn_s_setprio(1);
#pragma unroll
            for (int mi = 0; mi < 4; ++mi)
#pragma unroll
                for (int nj = 0; nj < 4; ++nj)
                    acc[mi][nj] = __builtin_amdgcn_mfma_f32_16x16x32_f16(af[mi], bf[nj], acc[mi][nj], 0, 0, 0);
            __builtin_amdgcn_s_setprio(0);
        }
        __builtin_amdgcn_s_barrier();
    }

    // epilogue: C/D layout col = lane&15, row = (lane>>4)*4 + j
    const int cl = lane & 15, g = lane >> 4;
#pragma unroll
    for (int mi = 0; mi < 4; ++mi) {
#pragma unroll
        for (int nj = 0; nj < 4; ++nj) {
            const int col = tn * 128 + wn + nj * 16 + cl;
            if (MODE == 1 && col >= DIMC) {
                // V chunk-tiled write: 4 consecutive kv at fixed d -> one 8B store
                const int gm0 = tm * 128 + wm + mi * 16 + g * 4;
                const int bb = gm0 / NKV;
                const int rr = gm0 - bb * NKV;
                const int vc = col - DIMC;
                f16x4 pk;
                pk[0] = (f16)acc[mi][nj][0]; pk[1] = (f16)acc[mi][nj][1];
                pk[2] = (f16)acc[mi][nj][2]; pk[3] = (f16)acc[mi][nj][3];
                *reinterpret_cast<f16x4*>(
                    Vt + ((((size_t)bb * 16 + (vc >> 6)) * NCHUNK + (rr >> 6)) * 64 + (vc & 63)) * 64 + (rr & 63)) = pk;
            } else {
#pragma unroll
                for (int j = 0; j < 4; ++j) {
                    const int gm = tm * 128 + wm + mi * 16 + g * 4 + j;
                    const float val = acc[mi][nj][j];
                    if (MODE == 0) {
                        const int bb = gm >> 11, rr = gm & 2047;
                        Cf16[(((size_t)bb * 16 + (col >> 6)) * NSEQ + rr) * 64 + (col & 63)] = (f16)val;
                    } else if (MODE == 1) {
                        const int bb = gm / NKV;
                        const int rr = gm - bb * NKV;
                        Cf16[(((size_t)bb * 16 + (col >> 6)) * NKV + rr) * 64 + (col & 63)] = (f16)val;
                    } else {
                        Cf32[(size_t)gm * DIMC + col] = val + bias[col];
                    }
                }
            }
        }
    }
}

// fused q + kv projection: grid (66, 24); by<16 -> kv (tm 0..65), by>=16 -> q (tm 0..63)
__global__ __launch_bounds__(256, 2)
void gemm_qkv(const f16* __restrict__ xn, const f16* __restrict__ wqT,
              const f16* __restrict__ wkvT, const f16* __restrict__ mem16,
              f16* __restrict__ q16, f16* __restrict__ k16, f16* __restrict__ vt16)
{
    __shared__ __align__(16) f16 As[2 * 128 * 64];
    __shared__ __align__(16) f16 Bs[2 * 128 * 64];
    if (blockIdx.y < 16) {
        gemm_body<1>(blockIdx.x, blockIdx.y, As, Bs, xn, wkvT, mem16, k16, vt16, nullptr, nullptr);
    } else {
        if (blockIdx.x >= 64) return;
        gemm_body<0>(blockIdx.x, blockIdx.y - 16, As, Bs, xn, wqT, nullptr, q16, nullptr, nullptr, nullptr);
    }
}

__global__ __launch_bounds__(256, 2)
void gemm_o(const f16* __restrict__ ao, const f16* __restrict__ woT,
            float* __restrict__ out, const float* __restrict__ bo)
{
    __shared__ __align__(16) f16 As[2 * 128 * 64];
    __shared__ __align__(16) f16 Bs[2 * 128 * 64];
    gemm_body<2>(blockIdx.x, blockIdx.y, As, Bs, ao, woT, nullptr, nullptr, nullptr, out, bo);
}

// ---------------- flash attention (r8/r11 known-good) ----------------
__global__ __launch_bounds__(512, 4)
void attn_kernel(const f16* __restrict__ q16, const f16* __restrict__ k16,
                 const f16* __restrict__ vt16, f16* __restrict__ ao16)
{
    __shared__ __align__(16) f16 Kb[3][64 * 64];
    __shared__ __align__(16) f16 Vb[3][64 * 64];

    const int raw = blockIdx.x;
    const int bh = (raw & 7) * 8 + ((raw >> 3) & 7);   // XCD co-location
    const int qt = raw >> 6;
    const int b = bh >> 4, h = bh & 15;
    const int tid = threadIdx.x, lane = tid & 63, w = tid >> 6;   // w = 0..7
    const int l31 = lane & 31, hi = lane >> 5;
    const int l3 = lane >> 3, l7 = lane & 7;
    const int gslot = (l7 ^ l3) * 8;

    const f16* kbase = k16  + (size_t)bh * NKV * 64;
    const f16* vbase = vt16 + (size_t)bh * NCHUNK * 4096;
    const f16* qbase = q16  + (size_t)bh * NSEQ * 64;

    const int srow = w * 8 + l3;
    const f16* kp = kbase + (size_t)srow * 64 + gslot;
    const f16* vp = vbase + (size_t)srow * 64 + gslot;

    f16x8 qf[4];
    {
        const int qrow = qt * 256 + w * 32 + l31;
#pragma unroll
        for (int ks = 0; ks < 4; ++ks)
            qf[ks] = *reinterpret_cast<const f16x8*>(
                qbase + (size_t)qrow * 64 + ks * 16 + hi * 8);
    }

    f32x16 Oa0 = {}, Oa1 = {};
    float lp0 = 0.0f, lp1 = 0.0f, lp2 = 0.0f, lp3 = 0.0f;

    f32x16 minus8;
#pragma unroll
    for (int r = 0; r < 16; ++r) minus8[r] = -8.0f;

#pragma unroll
    for (int c = 0; c < 2; ++c) {
        gld16(kp + (size_t)c * 4096, &Kb[c][w * 8 * 64]);
        gld16(vp + (size_t)c * 4096, &Vb[c][w * 8 * 64]);
    }

#if __has_builtin(__builtin_amdgcn_fdot2)
    const h16x2 ones = {(__fp16)1.0f, (__fp16)1.0f};
#endif

    int cur = 0, nxt = 2;
    for (int t = 0; t < NCHUNK; ++t) {
        if (t < NCHUNK - 1) asm volatile("s_waitcnt vmcnt(2)" ::: "memory");
        else                asm volatile("s_waitcnt vmcnt(0)" ::: "memory");
        __builtin_amdgcn_s_barrier();

        if (t + 2 < NCHUNK) {
            gld16(kp + (size_t)(t + 2) * 4096, &Kb[nxt][w * 8 * 64]);
            gld16(vp + (size_t)(t + 2) * 4096, &Vb[nxt][w * 8 * 64]);
        }
        const f16* Ks = Kb[cur];
        const f16* Vs = Vb[cur];

#pragma unroll
        for (int kb = 0; kb < 2; ++kb) {
            const int krow = kb * 32 + l31;
            f16x8 kf[4];
#pragma unroll
            for (int ks = 0; ks < 4; ++ks)
                kf[ks] = *reinterpret_cast<const f16x8*>(
                    &Ks[krow * 64 + ((2 * ks + hi) ^ (krow & 7)) * 8]);

            f32x16 sA;
            __builtin_amdgcn_s_setprio(1);
            sA = __builtin_amdgcn_mfma_f32_32x32x16_f16(kf[0], qf[0], minus8, 0, 0, 0);
#pragma unroll
            for (int ks = 1; ks < 4; ++ks)
                sA = __builtin_amdgcn_mfma_f32_32x32x16_f16(kf[ks], qf[ks], sA, 0, 0, 0);
            __builtin_amdgcn_s_setprio(0);

            float p[16];
#pragma unroll
            for (int r = 0; r < 16; ++r)
                p[r] = __builtin_amdgcn_exp2f(sA[r]);

            f16x8 pb[2];
#pragma unroll
            for (int s2 = 0; s2 < 2; ++s2) {
                u32 a  = pkrtz(p[s2 * 8 + 0], p[s2 * 8 + 1]);
                u32 b2 = pkrtz(p[s2 * 8 + 2], p[s2 * 8 + 3]);
                u32 c  = pkrtz(p[s2 * 8 + 4], p[s2 * 8 + 5]);
                u32 d  = pkrtz(p[s2 * 8 + 6], p[s2 * 8 + 7]);
                asm volatile("v_permlane32_swap_b32 %0, %1" : "+v"(a),  "+v"(c));
                asm volatile("v_permlane32_swap_b32 %0, %1" : "+v"(b2), "+v"(d));
#if __has_builtin(__builtin_amdgcn_fdot2)
                lp0 = __builtin_amdgcn_fdot2(__builtin_bit_cast(h16x2, a),  ones, lp0, false);
                lp1 = __builtin_amdgcn_fdot2(__builtin_bit_cast(h16x2, b2), ones, lp1, false);
                lp2 = __builtin_amdgcn_fdot2(__builtin_bit_cast(h16x2, c),  ones, lp2, false);
                lp3 = __builtin_amdgcn_fdot2(__builtin_bit_cast(h16x2, d),  ones, lp3, false);
#else
                {
                    h16x2 ha = __builtin_bit_cast(h16x2, a),  hb = __builtin_bit_cast(h16x2, b2);
                    h16x2 hc = __builtin_bit_cast(h16x2, c),  hd = __builtin_bit_cast(h16x2, d);
                    lp0 += (float)ha[0] + (float)ha[1];
                    lp1 += (float)hb[0] + (float)hb[1];
                    lp2 += (float)hc[0] + (float)hc[1];
                    lp3 += (float)hd[0] + (float)hd[1];
                }
#endif
                u32x4 wv = {a, b2, c, d};
                pb[s2] = __builtin_bit_cast(f16x8, wv);
            }

#pragma unroll
            for (int s2 = 0; s2 < 2; ++s2) {
                const int s = kb * 2 + s2;
                const int vr1 = 32 + l31;
                const f16x8 vf0 = *reinterpret_cast<const f16x8*>(
                    &Vs[l31 * 64 + ((2 * s + hi) ^ (l31 & 7)) * 8]);
                const f16x8 vf1 = *reinterpret_cast<const f16x8*>(
                    &Vs[vr1 * 64 + ((2 * s + hi) ^ (vr1 & 7)) * 8]);
                __builtin_amdgcn_s_setprio(1);
                Oa0 = __builtin_amdgcn_mfma_f32_32x32x16_f16(vf0, pb[s2], Oa0, 0, 0, 0);
                Oa1 = __builtin_amdgcn_mfma_f32_32x32x16_f16(vf1, pb[s2], Oa1, 0, 0, 0);
                __builtin_amdgcn_s_setprio(0);
            }
        }
        cur = (cur == 2) ? 0 : cur + 1;
        nxt = (nxt == 2) ? 0 : nxt + 1;
    }

    float l0 = (lp0 + lp1) + (lp2 + lp3);
    l0 += __shfl_xor(l0, 32, 64);
    const float rinv = 1.0f / l0;
    const int qrow = qt * 256 + w * 32 + l31;
#pragma unroll
    for (int rq = 0; rq < 4; ++rq) {
        const int d0 = rq * 8 + hi * 4;
        f16x4 pk;
        pk[0] = (f16)(Oa0[rq * 4 + 0] * rinv);
        pk[1] = (f16)(Oa0[rq * 4 + 1] * rinv);
        pk[2] = (f16)(Oa0[rq * 4 + 2] * rinv);
        pk[3] = (f16)(Oa0[rq * 4 + 3] * rinv);
        *reinterpret_cast<f16x4*>(
            ao16 + ((size_t)(b * NSEQ + qrow)) * DIMC + h * 64 + d0) = pk;
    }
#pragma unroll
    for (int rq = 0; rq < 4; ++rq) {
        const int d0 = 32 + rq * 8 + hi * 4;
        f16x4 pk;
        pk[0] = (f16)(Oa1[rq * 4 + 0] * rinv);
        pk[1] = (f16)(Oa1[rq * 4 + 1] * rinv);
        pk[2] = (f16)(Oa1[rq * 4 + 2] * rinv);
        pk[3] = (f16)(Oa1[rq * 4 + 3] * rinv);
        *reinterpret_cast<f16x4*>(
            ao16 + ((size_t)(b * NSEQ + qrow)) * DIMC + h * 64 + d0) = pk;
    }
}

// ---------------- launch ----------------
extern "C" void kernel_launch(void* const* d_in, const int* in_sizes, int n_in,
                              void* d_out, int out_size, void* d_ws, size_t ws_size,
                              hipStream_t stream)
{
    const float* x        = (const float*)d_in[0];
    const float* memories = (const float*)d_in[2];
    const float* ln_gamma = (const float*)d_in[3];
    const float* ln_beta  = (const float*)d_in[4];
    const float* Wq       = (const float*)d_in[5];
    const float* Wkv      = (const float*)d_in[6];
    const float* Wo       = (const float*)d_in[7];
    const float* bo       = (const float*)d_in[8];
    float* out = (float*)d_out;

    char* ws = (char*)d_ws;
    f16* xn16  = (f16*)(ws);                          // 16 MiB (reused as ao16)
    f16* q16   = (f16*)(ws + (16ull << 20));          // 16 MiB, head-major
    f16* k16   = (f16*)(ws + (32ull << 20));          // 16.5 MiB, head-major
    f16* vt16  = (f16*)(ws + (49ull << 20));          // 16.5 MiB, chunk-tiled
    f16* wqT   = (f16*)(ws + (66ull << 20));          // 2 MiB
    f16* wkvT  = (f16*)(ws + (68ull << 20));          // 4 MiB
    f16* woT   = (f16*)(ws + (72ull << 20));          // 2 MiB
    f16* mem16 = (f16*)(ws + (74ull << 20));          // 128 KiB
    f16* ao16  = xn16;   // xn16 dead after qkv GEMM

    // fused prep: Wq/Wkv/Wo transpose+cast (+scale folds) and memories cast
    prep_kernel<<<dim3(64, 97), dim3(32, 8), 0, stream>>>(
        Wq, Wkv, Wo, memories, wqT, wkvT, woT, mem16);

    // layernorm
    ln_kernel<<<NBATCH * NSEQ, 256, 0, stream>>>(x, ln_gamma, ln_beta, xn16);

    // fused q & kv projections (head-major / chunk-tiled outputs)
    gemm_qkv<<<dim3(66, 24), 256, 0, stream>>>(xn16, wqT, wkvT, mem16, q16, k16, vt16);

    // attention -> ao16 (natural layout)
    attn_kernel<<<dim3(512), 512, 0, stream>>>(q16, k16, vt16, ao16);

    // out = ao @ Wo + bo
    gemm_o<<<dim3(64, 8), 256, 0, stream>>>(ao16, woT, out, bo);

    (void)in_sizes; (void)n_in; (void)out_size; (void)ws_size;
}

// Round 14
// 192.942 us; speedup vs baseline: 1.0478x; 1.0478x over previous
//
#include <hip/hip_runtime.h>

using f16 = _Float16;
typedef _Float16 f16x8 __attribute__((ext_vector_type(8)));
typedef _Float16 f16x4 __attribute__((ext_vector_type(4)));
typedef float f32x4 __attribute__((ext_vector_type(4)));
typedef float f32x16 __attribute__((ext_vector_type(16)));
typedef uint32_t u32;
typedef unsigned int u32x4 __attribute__((ext_vector_type(4)));
typedef __fp16 h16x2 __attribute__((ext_vector_type(2)));

constexpr int DIMC   = 1024;
constexpr int NSEQ   = 2048;
constexpr int NKV    = 2112;   // 2048 + 64 memories = 33 chunks of 64
constexpr int NCHUNK = 33;
constexpr int NBATCH = 4;

__device__ __forceinline__ int swz8(int row, int slot) { return slot ^ (row & 7); }

__device__ __forceinline__ u32 pkrtz(float a, float b) {
    h16x2 t = __builtin_amdgcn_cvt_pkrtz(a, b);
    return __builtin_bit_cast(u32, t);
}

// async 16B global -> LDS (linear dest = wave-uniform base + lane*16)
__device__ __forceinline__ void gld16(const f16* g, f16* l) {
    __builtin_amdgcn_global_load_lds(
        (const __attribute__((address_space(1))) u32*)g,
        (__attribute__((address_space(3))) u32*)l,
        16, 0, 0);
}

// ---------------- LayerNorm fp32 -> fp16 ----------------
__global__ __launch_bounds__(256)
void ln_kernel(const float* __restrict__ x, const float* __restrict__ gamma,
               const float* __restrict__ beta, f16* __restrict__ xn)
{
    const int row = blockIdx.x;
    const int tid = threadIdx.x;
    const float4 v = *reinterpret_cast<const float4*>(x + (size_t)row * DIMC + tid * 4);
    float s  = v.x + v.y + v.z + v.w;
    float ss = v.x*v.x + v.y*v.y + v.z*v.z + v.w*v.w;
#pragma unroll
    for (int off = 1; off < 64; off <<= 1) {
        s  += __shfl_xor(s,  off, 64);
        ss += __shfl_xor(ss, off, 64);
    }
    __shared__ float ps[4], pss[4];
    const int w = tid >> 6;
    if ((tid & 63) == 0) { ps[w] = s; pss[w] = ss; }
    __syncthreads();
    s  = ps[0]  + ps[1]  + ps[2]  + ps[3];
    ss = pss[0] + pss[1] + pss[2] + pss[3];
    const float mu   = s * (1.0f / 1024.0f);
    const float var  = ss * (1.0f / 1024.0f) - mu * mu;
    const float rstd = rsqrtf(var + 1e-5f);
    const float4 gv = *reinterpret_cast<const float4*>(gamma + tid * 4);
    const float4 bv = *reinterpret_cast<const float4*>(beta  + tid * 4);
    f16x4 o;
    o[0] = (f16)((v.x - mu) * rstd * gv.x + bv.x);
    o[1] = (f16)((v.y - mu) * rstd * gv.y + bv.y);
    o[2] = (f16)((v.z - mu) * rstd * gv.z + bv.z);
    o[3] = (f16)((v.w - mu) * rstd * gv.w + bv.w);
    *reinterpret_cast<f16x4*>(xn + (size_t)row * DIMC + tid * 4) = o;
}

// ---------------- fused weight transpose+cast + memories cast ----------------
__device__ __forceinline__ void transpose_tile(
    const float* __restrict__ in, f16* __restrict__ out,
    int R, int C, float scale, int bx, int by)
{
    __shared__ float tile[32][33];
    const int c0 = bx * 32;
    const int r0 = by * 32;
    const int tx = threadIdx.x;       // 0..31
    const int ty = threadIdx.y;       // 0..7
#pragma unroll
    for (int i = 0; i < 4; ++i)
        tile[ty + i * 8][tx] = in[(size_t)(r0 + ty + i * 8) * C + c0 + tx];
    __syncthreads();
#pragma unroll
    for (int i = 0; i < 4; ++i)
        out[(size_t)(c0 + ty + i * 8) * R + r0 + tx] = (f16)(tile[tx][ty + i * 8] * scale);
}

__global__ __launch_bounds__(256)
void prep_kernel(const float* __restrict__ Wq, const float* __restrict__ Wkv,
                 const float* __restrict__ Wo, const float* __restrict__ mem,
                 f16* __restrict__ wqT, f16* __restrict__ wkvT,
                 f16* __restrict__ woT, f16* __restrict__ mem16)
{
    const int bx = blockIdx.x, by = blockIdx.y;
    if (by < 32) {
        if (bx < 32) transpose_tile(Wq, wqT, 1024, 1024, 0.125f * 1.44269504088896341f, bx, by);
    } else if (by < 64) {
        transpose_tile(Wkv, wkvT, 1024, 2048, 1.0f, bx, by - 32);
    } else if (by < 96) {
        if (bx < 32) transpose_tile(Wo, woT, 1024, 1024, 1.0f, bx, by - 64);
    } else {
        const int tid = threadIdx.y * 32 + threadIdx.x;
        const int i = bx * 256 + tid;
        const float4 v = *reinterpret_cast<const float4*>(mem + (size_t)i * 4);
        f16x4 o; o[0] = (f16)v.x; o[1] = (f16)v.y; o[2] = (f16)v.z; o[3] = (f16)v.w;
        *reinterpret_cast<f16x4*>(mem16 + (size_t)i * 4) = o;
    }
}

// ---------------- MFMA GEMM body (r11-exact): C[M,N] = A[M,K=1024] * BT[N,K]^T ----
// MODE 0: q proj -> head-major [b][h][n][64]
// MODE 1: kv proj -> K head-major [b][h][kv][64]; V chunk-tiled [b][h][33][64d][64kv]
// MODE 2: out proj -> fp32 + bias, natural layout
template<int MODE>
__device__ __forceinline__ void gemm_body(
    int tm, int tn, f16* As, f16* Bs,
    const f16* __restrict__ A, const f16* __restrict__ BT,
    const f16* __restrict__ mem16,
    f16* __restrict__ Cf16, f16* __restrict__ Vt,
    float* __restrict__ Cf32, const float* __restrict__ bias)
{
    const int tid = threadIdx.x;
    const int lane = tid & 63, w = tid >> 6;
    const int wm = (w >> 1) * 64, wn = (w & 1) * 64;
    const int l3 = lane >> 3, l7 = lane & 7;
    const int gslot = (l7 ^ l3) * 8;          // pre-swizzled k-offset (elems)

    f32x4 acc[4][4] = {};

    const f16* ag[4];
    const f16* bg[4];
#pragma unroll
    for (int i = 0; i < 4; ++i) {
        const int rl = w * 32 + i * 8 + l3;
        const int gm = tm * 128 + rl;
        if (MODE == 1) {
            const int bb = gm / NKV;
            const int rr = gm - bb * NKV;
            ag[i] = ((rr < NSEQ) ? (A + ((size_t)bb * NSEQ + rr) * DIMC)
                                 : (mem16 + (size_t)(rr - NSEQ) * DIMC)) + gslot;
        } else {
            ag[i] = A + (size_t)gm * DIMC + gslot;
        }
        bg[i] = BT + (size_t)(tn * 128 + rl) * DIMC + gslot;
    }

    for (int kt = 0; kt < DIMC; kt += 64) {
#pragma unroll
        for (int i = 0; i < 4; ++i) {
            gld16(ag[i] + kt, &As[(w * 32 + i * 8) * 64]);
            gld16(bg[i] + kt, &Bs[(w * 32 + i * 8) * 64]);
        }
        asm volatile("s_waitcnt vmcnt(0)" ::: "memory");
        __syncthreads();
#pragma unroll
        for (int kk = 0; kk < 2; ++kk) {
            f16x8 af[4], bf[4];
            const int rsel  = lane & 15;
            const int slot0 = (lane >> 4) + kk * 4;
#pragma unroll
            for (int mi = 0; mi < 4; ++mi) {
                const int row = wm + mi * 16 + rsel;
                af[mi] = *reinterpret_cast<const f16x8*>(&As[row * 64 + swz8(row, slot0) * 8]);
            }
#pragma unroll
            for (int nj = 0; nj < 4; ++nj) {
                const int row = wn + nj * 16 + rsel;
                bf[nj] = *reinterpret_cast<const f16x8*>(&Bs[row * 64 + swz8(row, slot0) * 8]);
            }
            __builtin_amdgcn_s_setprio(1);
#pragma unroll
            for (int mi = 0; mi < 4; ++mi)
#pragma unroll
                for (int nj = 0; nj < 4; ++nj)
                    acc[mi][nj] = __builtin_amdgcn_mfma_f32_16x16x32_f16(af[mi], bf[nj], acc[mi][nj], 0, 0, 0);
            __builtin_amdgcn_s_setprio(0);
        }
        __syncthreads();
    }

    // epilogue: C/D layout col = lane&15, row = (lane>>4)*4 + j
    const int cl = lane & 15, g = lane >> 4;
#pragma unroll
    for (int mi = 0; mi < 4; ++mi) {
#pragma unroll
        for (int nj = 0; nj < 4; ++nj) {
            const int col = tn * 128 + wn + nj * 16 + cl;
            if (MODE == 1 && col >= DIMC) {
                // V chunk-tiled write: 4 consecutive kv at fixed d -> one 8B store
                const int gm0 = tm * 128 + wm + mi * 16 + g * 4;
                const int bb = gm0 / NKV;
                const int rr = gm0 - bb * NKV;
                const int vc = col - DIMC;
                f16x4 pk;
                pk[0] = (f16)acc[mi][nj][0]; pk[1] = (f16)acc[mi][nj][1];
                pk[2] = (f16)acc[mi][nj][2]; pk[3] = (f16)acc[mi][nj][3];
                *reinterpret_cast<f16x4*>(
                    Vt + ((((size_t)bb * 16 + (vc >> 6)) * NCHUNK + (rr >> 6)) * 64 + (vc & 63)) * 64 + (rr & 63)) = pk;
            } else {
#pragma unroll
                for (int j = 0; j < 4; ++j) {
                    const int gm = tm * 128 + wm + mi * 16 + g * 4 + j;
                    const float val = acc[mi][nj][j];
                    if (MODE == 0) {
                        const int bb = gm >> 11, rr = gm & 2047;
                        Cf16[(((size_t)bb * 16 + (col >> 6)) * NSEQ + rr) * 64 + (col & 63)] = (f16)val;
                    } else if (MODE == 1) {
                        const int bb = gm / NKV;
                        const int rr = gm - bb * NKV;
                        Cf16[(((size_t)bb * 16 + (col >> 6)) * NKV + rr) * 64 + (col & 63)] = (f16)val;
                    } else {
                        Cf32[(size_t)gm * DIMC + col] = val + bias[col];
                    }
                }
            }
        }
    }
}

// fused q + kv projection, XCD-slab swizzle: 1-D grid 1584 blocks.
// xcd = bid&7 owns g in [xcd*198, (xcd+1)*198): bx = g/24 spans ~8-9 consecutive
// A-panels (2.1-2.3 MB -> fits the XCD's private 4 MB L2) swept over all by.
// by<16 -> kv (tm 0..65); by>=16 -> q (tm 0..63; bx>=64 idle, 16 blocks).
__global__ __launch_bounds__(256, 3)
void gemm_qkv(const f16* __restrict__ xn, const f16* __restrict__ wqT,
              const f16* __restrict__ wkvT, const f16* __restrict__ mem16,
              f16* __restrict__ q16, f16* __restrict__ k16, f16* __restrict__ vt16)
{
    __shared__ __align__(16) f16 As[128 * 64];
    __shared__ __align__(16) f16 Bs[128 * 64];
    const int bid = blockIdx.x;
    const int g = (bid & 7) * 198 + (bid >> 3);   // bijective: [0,1584)
    const int by = g % 24;
    const int bx = g / 24;                        // 0..65
    if (by < 16) {
        gemm_body<1>(bx, by, As, Bs, xn, wkvT, mem16, k16, vt16, nullptr, nullptr);
    } else {
        if (bx >= 64) return;
        gemm_body<0>(bx, by - 16, As, Bs, xn, wqT, nullptr, q16, nullptr, nullptr, nullptr);
    }
}

// out proj, XCD-slab swizzle: 1-D grid 512. xcd owns bx in [xcd*8, xcd*8+8)
// (A-slab 2 MB, L2-resident) swept over all 8 by.
__global__ __launch_bounds__(256, 3)
void gemm_o(const f16* __restrict__ ao, const f16* __restrict__ woT,
            float* __restrict__ out, const float* __restrict__ bo)
{
    __shared__ __align__(16) f16 As[128 * 64];
    __shared__ __align__(16) f16 Bs[128 * 64];
    const int bid = blockIdx.x;
    const int g = (bid & 7) * 64 + (bid >> 3);    // bijective: [0,512)
    const int by = g & 7;
    const int bx = g >> 3;                        // 0..63
    gemm_body<2>(bx, by, As, Bs, ao, woT, nullptr, nullptr, nullptr, out, bo);
}

// ---------------- flash attention (r8/r11 known-good) ----------------
__global__ __launch_bounds__(512, 4)
void attn_kernel(const f16* __restrict__ q16, const f16* __restrict__ k16,
                 const f16* __restrict__ vt16, f16* __restrict__ ao16)
{
    __shared__ __align__(16) f16 Kb[3][64 * 64];
    __shared__ __align__(16) f16 Vb[3][64 * 64];

    const int raw = blockIdx.x;
    const int bh = (raw & 7) * 8 + ((raw >> 3) & 7);   // XCD co-location
    const int qt = raw >> 6;
    const int b = bh >> 4, h = bh & 15;
    const int tid = threadIdx.x, lane = tid & 63, w = tid >> 6;   // w = 0..7
    const int l31 = lane & 31, hi = lane >> 5;
    const int l3 = lane >> 3, l7 = lane & 7;
    const int gslot = (l7 ^ l3) * 8;

    const f16* kbase = k16  + (size_t)bh * NKV * 64;
    const f16* vbase = vt16 + (size_t)bh * NCHUNK * 4096;
    const f16* qbase = q16  + (size_t)bh * NSEQ * 64;

    const int srow = w * 8 + l3;
    const f16* kp = kbase + (size_t)srow * 64 + gslot;
    const f16* vp = vbase + (size_t)srow * 64 + gslot;

    f16x8 qf[4];
    {
        const int qrow = qt * 256 + w * 32 + l31;
#pragma unroll
        for (int ks = 0; ks < 4; ++ks)
            qf[ks] = *reinterpret_cast<const f16x8*>(
                qbase + (size_t)qrow * 64 + ks * 16 + hi * 8);
    }

    f32x16 Oa0 = {}, Oa1 = {};
    float lp0 = 0.0f, lp1 = 0.0f, lp2 = 0.0f, lp3 = 0.0f;

    f32x16 minus8;
#pragma unroll
    for (int r = 0; r < 16; ++r) minus8[r] = -8.0f;

#pragma unroll
    for (int c = 0; c < 2; ++c) {
        gld16(kp + (size_t)c * 4096, &Kb[c][w * 8 * 64]);
        gld16(vp + (size_t)c * 4096, &Vb[c][w * 8 * 64]);
    }

#if __has_builtin(__builtin_amdgcn_fdot2)
    const h16x2 ones = {(__fp16)1.0f, (__fp16)1.0f};
#endif

    int cur = 0, nxt = 2;
    for (int t = 0; t < NCHUNK; ++t) {
        if (t < NCHUNK - 1) asm volatile("s_waitcnt vmcnt(2)" ::: "memory");
        else                asm volatile("s_waitcnt vmcnt(0)" ::: "memory");
        __builtin_amdgcn_s_barrier();

        if (t + 2 < NCHUNK) {
            gld16(kp + (size_t)(t + 2) * 4096, &Kb[nxt][w * 8 * 64]);
            gld16(vp + (size_t)(t + 2) * 4096, &Vb[nxt][w * 8 * 64]);
        }
        const f16* Ks = Kb[cur];
        const f16* Vs = Vb[cur];

#pragma unroll
        for (int kb = 0; kb < 2; ++kb) {
            const int krow = kb * 32 + l31;
            f16x8 kf[4];
#pragma unroll
            for (int ks = 0; ks < 4; ++ks)
                kf[ks] = *reinterpret_cast<const f16x8*>(
                    &Ks[krow * 64 + ((2 * ks + hi) ^ (krow & 7)) * 8]);

            f32x16 sA;
            __builtin_amdgcn_s_setprio(1);
            sA = __builtin_amdgcn_mfma_f32_32x32x16_f16(kf[0], qf[0], minus8, 0, 0, 0);
#pragma unroll
            for (int ks = 1; ks < 4; ++ks)
                sA = __builtin_amdgcn_mfma_f32_32x32x16_f16(kf[ks], qf[ks], sA, 0, 0, 0);
            __builtin_amdgcn_s_setprio(0);

            float p[16];
#pragma unroll
            for (int r = 0; r < 16; ++r)
                p[r] = __builtin_amdgcn_exp2f(sA[r]);

            f16x8 pb[2];
#pragma unroll
            for (int s2 = 0; s2 < 2; ++s2) {
                u32 a  = pkrtz(p[s2 * 8 + 0], p[s2 * 8 + 1]);
                u32 b2 = pkrtz(p[s2 * 8 + 2], p[s2 * 8 + 3]);
                u32 c  = pkrtz(p[s2 * 8 + 4], p[s2 * 8 + 5]);
                u32 d  = pkrtz(p[s2 * 8 + 6], p[s2 * 8 + 7]);
                asm volatile("v_permlane32_swap_b32 %0, %1" : "+v"(a),  "+v"(c));
                asm volatile("v_permlane32_swap_b32 %0, %1" : "+v"(b2), "+v"(d));
#if __has_builtin(__builtin_amdgcn_fdot2)
                lp0 = __builtin_amdgcn_fdot2(__builtin_bit_cast(h16x2, a),  ones, lp0, false);
                lp1 = __builtin_amdgcn_fdot2(__builtin_bit_cast(h16x2, b2), ones, lp1, false);
                lp2 = __builtin_amdgcn_fdot2(__builtin_bit_cast(h16x2, c),  ones, lp2, false);
                lp3 = __builtin_amdgcn_fdot2(__builtin_bit_cast(h16x2, d),  ones, lp3, false);
#else
                {
                    h16x2 ha = __builtin_bit_cast(h16x2, a),  hb = __builtin_bit_cast(h16x2, b2);
                    h16x2 hc = __builtin_bit_cast(h16x2, c),  hd = __builtin_bit_cast(h16x2, d);
                    lp0 += (float)ha[0] + (float)ha[1];
                    lp1 += (float)hb[0] + (float)hb[1];
                    lp2 += (float)hc[0] + (float)hc[1];
                    lp3 += (float)hd[0] + (float)hd[1];
                }
#endif
                u32x4 wv = {a, b2, c, d};
                pb[s2] = __builtin_bit_cast(f16x8, wv);
            }

#pragma unroll
            for (int s2 = 0; s2 < 2; ++s2) {
                const int s = kb * 2 + s2;
                const int vr1 = 32 + l31;
                const f16x8 vf0 = *reinterpret_cast<const f16x8*>(
                    &Vs[l31 * 64 + ((2 * s + hi) ^ (l31 & 7)) * 8]);
                const f16x8 vf1 = *reinterpret_cast<const f16x8*>(
                    &Vs[vr1 * 64 + ((2 * s + hi) ^ (vr1 & 7)) * 8]);
                __builtin_amdgcn_s_setprio(1);
                Oa0 = __builtin_amdgcn_mfma_f32_32x32x16_f16(vf0, pb[s2], Oa0, 0, 0, 0);
                Oa1 = __builtin_amdgcn_mfma_f32_32x32x16_f16(vf1, pb[s2], Oa1, 0, 0, 0);
                __builtin_amdgcn_s_setprio(0);
            }
        }
        cur = (cur == 2) ? 0 : cur + 1;
        nxt = (nxt == 2) ? 0 : nxt + 1;
    }

    float l0 = (lp0 + lp1) + (lp2 + lp3);
    l0 += __shfl_xor(l0, 32, 64);
    const float rinv = 1.0f / l0;
    const int qrow = qt * 256 + w * 32 + l31;
#pragma unroll
    for (int rq = 0; rq < 4; ++rq) {
        const int d0 = rq * 8 + hi * 4;
        f16x4 pk;
        pk[0] = (f16)(Oa0[rq * 4 + 0] * rinv);
        pk[1] = (f16)(Oa0[rq * 4 + 1] * rinv);
        pk[2] = (f16)(Oa0[rq * 4 + 2] * rinv);
        pk[3] = (f16)(Oa0[rq * 4 + 3] * rinv);
        *reinterpret_cast<f16x4*>(
            ao16 + ((size_t)(b * NSEQ + qrow)) * DIMC + h * 64 + d0) = pk;
    }
#pragma unroll
    for (int rq = 0; rq < 4; ++rq) {
        const int d0 = 32 + rq * 8 + hi * 4;
        f16x4 pk;
        pk[0] = (f16)(Oa1[rq * 4 + 0] * rinv);
        pk[1] = (f16)(Oa1[rq * 4 + 1] * rinv);
        pk[2] = (f16)(Oa1[rq * 4 + 2] * rinv);
        pk[3] = (f16)(Oa1[rq * 4 + 3] * rinv);
        *reinterpret_cast<f16x4*>(
            ao16 + ((size_t)(b * NSEQ + qrow)) * DIMC + h * 64 + d0) = pk;
    }
}

// ---------------- launch ----------------
extern "C" void kernel_launch(void* const* d_in, const int* in_sizes, int n_in,
                              void* d_out, int out_size, void* d_ws, size_t ws_size,
                              hipStream_t stream)
{
    const float* x        = (const float*)d_in[0];
    const float* memories = (const float*)d_in[2];
    const float* ln_gamma = (const float*)d_in[3];
    const float* ln_beta  = (const float*)d_in[4];
    const float* Wq       = (const float*)d_in[5];
    const float* Wkv      = (const float*)d_in[6];
    const float* Wo       = (const float*)d_in[7];
    const float* bo       = (const float*)d_in[8];
    float* out = (float*)d_out;

    char* ws = (char*)d_ws;
    f16* xn16  = (f16*)(ws);                          // 16 MiB (reused as ao16)
    f16* q16   = (f16*)(ws + (16ull << 20));          // 16 MiB, head-major
    f16* k16   = (f16*)(ws + (32ull << 20));          // 16.5 MiB, head-major
    f16* vt16  = (f16*)(ws + (49ull << 20));          // 16.5 MiB, chunk-tiled
    f16* wqT   = (f16*)(ws + (66ull << 20));          // 2 MiB
    f16* wkvT  = (f16*)(ws + (68ull << 20));          // 4 MiB
    f16* woT   = (f16*)(ws + (72ull << 20));          // 2 MiB
    f16* mem16 = (f16*)(ws + (74ull << 20));          // 128 KiB
    f16* ao16  = xn16;   // xn16 dead after qkv GEMM

    // fused prep: Wq/Wkv/Wo transpose+cast (+scale folds) and memories cast
    prep_kernel<<<dim3(64, 97), dim3(32, 8), 0, stream>>>(
        Wq, Wkv, Wo, memories, wqT, wkvT, woT, mem16);

    // layernorm
    ln_kernel<<<NBATCH * NSEQ, 256, 0, stream>>>(x, ln_gamma, ln_beta, xn16);

    // fused q & kv projections (XCD-slab swizzled grid)
    gemm_qkv<<<dim3(1584), 256, 0, stream>>>(xn16, wqT, wkvT, mem16, q16, k16, vt16);

    // attention -> ao16 (natural layout)
    attn_kernel<<<dim3(512), 512, 0, stream>>>(q16, k16, vt16, ao16);

    // out = ao @ Wo + bo (XCD-slab swizzled grid)
    gemm_o<<<dim3(512), 256, 0, stream>>>(ao16, woT, out, bo);

    (void)in_sizes; (void)n_in; (void)out_size; (void)ws_size;
}

// Round 15
// 186.788 us; speedup vs baseline: 1.0823x; 1.0329x over previous
//
#include <hip/hip_runtime.h>

using f16 = _Float16;
typedef _Float16 f16x8 __attribute__((ext_vector_type(8)));
typedef _Float16 f16x4 __attribute__((ext_vector_type(4)));
typedef float f32x4 __attribute__((ext_vector_type(4)));
typedef float f32x16 __attribute__((ext_vector_type(16)));
typedef uint32_t u32;
typedef unsigned int u32x4 __attribute__((ext_vector_type(4)));
typedef __fp16 h16x2 __attribute__((ext_vector_type(2)));

constexpr int DIMC   = 1024;
constexpr int NSEQ   = 2048;
constexpr int NKV    = 2112;   // 2048 + 64 memories = 33 chunks of 64
constexpr int NCHUNK = 33;
constexpr int NBATCH = 4;

__device__ __forceinline__ int swz8(int row, int slot) { return slot ^ (row & 7); }

__device__ __forceinline__ u32 pkrtz(float a, float b) {
    h16x2 t = __builtin_amdgcn_cvt_pkrtz(a, b);
    return __builtin_bit_cast(u32, t);
}

// async 16B global -> LDS (linear dest = wave-uniform base + lane*16)
__device__ __forceinline__ void gld16(const f16* g, f16* l) {
    __builtin_amdgcn_global_load_lds(
        (const __attribute__((address_space(1))) u32*)g,
        (__attribute__((address_space(3))) u32*)l,
        16, 0, 0);
}

// ---------------- fused prep + LayerNorm ----------------
// grid: [0,2048)   -> LN, 4 rows/block, one wave per row (shuffle-only reduce)
//       [2048, +6208) -> weight transposes + memories cast (prep grid 64 x 97)
__device__ __forceinline__ void transpose_tile(
    const float* __restrict__ in, f16* __restrict__ out,
    int R, int C, float scale, int bx, int by, int tx, int ty)
{
    __shared__ float tile[32][33];
    const int c0 = bx * 32;
    const int r0 = by * 32;
#pragma unroll
    for (int i = 0; i < 4; ++i)
        tile[ty + i * 8][tx] = in[(size_t)(r0 + ty + i * 8) * C + c0 + tx];
    __syncthreads();
#pragma unroll
    for (int i = 0; i < 4; ++i)
        out[(size_t)(c0 + ty + i * 8) * R + r0 + tx] = (f16)(tile[tx][ty + i * 8] * scale);
}

__global__ __launch_bounds__(256)
void prep_ln_kernel(const float* __restrict__ x, const float* __restrict__ gamma,
                    const float* __restrict__ beta,
                    const float* __restrict__ Wq, const float* __restrict__ Wkv,
                    const float* __restrict__ Wo, const float* __restrict__ mem,
                    f16* __restrict__ xn, f16* __restrict__ wqT, f16* __restrict__ wkvT,
                    f16* __restrict__ woT, f16* __restrict__ mem16)
{
    const int bid = blockIdx.x;
    const int tid = threadIdx.x;
    if (bid < 2048) {
        // -------- LayerNorm: one wave per row, no LDS, no syncthreads --------
        const int wv = tid >> 6, lane = tid & 63;
        const int row = bid * 4 + wv;
        const float* xr = x + (size_t)row * DIMC;
        float4 v[4];
        float s = 0.0f, ss = 0.0f;
#pragma unroll
        for (int j = 0; j < 4; ++j) {
            v[j] = *reinterpret_cast<const float4*>(xr + lane * 4 + j * 256);
            s  += (v[j].x + v[j].y) + (v[j].z + v[j].w);
            ss += (v[j].x * v[j].x + v[j].y * v[j].y) + (v[j].z * v[j].z + v[j].w * v[j].w);
        }
#pragma unroll
        for (int off = 1; off < 64; off <<= 1) {
            s  += __shfl_xor(s,  off, 64);
            ss += __shfl_xor(ss, off, 64);
        }
        const float mu   = s * (1.0f / 1024.0f);
        const float var  = ss * (1.0f / 1024.0f) - mu * mu;
        const float rstd = rsqrtf(var + 1e-5f);
        f16* xo = xn + (size_t)row * DIMC;
#pragma unroll
        for (int j = 0; j < 4; ++j) {
            const float4 gv = *reinterpret_cast<const float4*>(gamma + lane * 4 + j * 256);
            const float4 bv = *reinterpret_cast<const float4*>(beta  + lane * 4 + j * 256);
            f16x4 o;
            o[0] = (f16)((v[j].x - mu) * rstd * gv.x + bv.x);
            o[1] = (f16)((v[j].y - mu) * rstd * gv.y + bv.y);
            o[2] = (f16)((v[j].z - mu) * rstd * gv.z + bv.z);
            o[3] = (f16)((v[j].w - mu) * rstd * gv.w + bv.w);
            *reinterpret_cast<f16x4*>(xo + lane * 4 + j * 256) = o;
        }
    } else {
        // -------- prep: transposes + memories cast --------
        const int pid = bid - 2048;
        const int bx = pid & 63, by = pid >> 6;     // 64 x 97
        const int tx = tid & 31, ty = tid >> 5;
        if (by < 32) {
            if (bx < 32) transpose_tile(Wq, wqT, 1024, 1024, 0.125f * 1.44269504088896341f, bx, by, tx, ty);
        } else if (by < 64) {
            transpose_tile(Wkv, wkvT, 1024, 2048, 1.0f, bx, by - 32, tx, ty);
        } else if (by < 96) {
            if (bx < 32) transpose_tile(Wo, woT, 1024, 1024, 1.0f, bx, by - 64, tx, ty);
        } else {
            const int i = bx * 256 + tid;
            const float4 v = *reinterpret_cast<const float4*>(mem + (size_t)i * 4);
            f16x4 o; o[0] = (f16)v.x; o[1] = (f16)v.y; o[2] = (f16)v.z; o[3] = (f16)v.w;
            *reinterpret_cast<f16x4*>(mem16 + (size_t)i * 4) = o;
        }
    }
}

// ---------------- MFMA GEMM body (r11-exact): C[M,N] = A[M,K=1024] * BT[N,K]^T ----
// MODE 0: q proj -> head-major [b][h][n][64]
// MODE 1: kv proj -> K head-major [b][h][kv][64]; V chunk-tiled [b][h][33][64d][64kv]
// MODE 2: out proj -> fp32 + bias, natural layout
template<int MODE>
__device__ __forceinline__ void gemm_body(
    int tm, int tn, f16* As, f16* Bs,
    const f16* __restrict__ A, const f16* __restrict__ BT,
    const f16* __restrict__ mem16,
    f16* __restrict__ Cf16, f16* __restrict__ Vt,
    float* __restrict__ Cf32, const float* __restrict__ bias)
{
    const int tid = threadIdx.x;
    const int lane = tid & 63, w = tid >> 6;
    const int wm = (w >> 1) * 64, wn = (w & 1) * 64;
    const int l3 = lane >> 3, l7 = lane & 7;
    const int gslot = (l7 ^ l3) * 8;          // pre-swizzled k-offset (elems)

    f32x4 acc[4][4] = {};

    const f16* ag[4];
    const f16* bg[4];
#pragma unroll
    for (int i = 0; i < 4; ++i) {
        const int rl = w * 32 + i * 8 + l3;
        const int gm = tm * 128 + rl;
        if (MODE == 1) {
            const int bb = gm / NKV;
            const int rr = gm - bb * NKV;
            ag[i] = ((rr < NSEQ) ? (A + ((size_t)bb * NSEQ + rr) * DIMC)
                                 : (mem16 + (size_t)(rr - NSEQ) * DIMC)) + gslot;
        } else {
            ag[i] = A + (size_t)gm * DIMC + gslot;
        }
        bg[i] = BT + (size_t)(tn * 128 + rl) * DIMC + gslot;
    }

    for (int kt = 0; kt < DIMC; kt += 64) {
#pragma unroll
        for (int i = 0; i < 4; ++i) {
            gld16(ag[i] + kt, &As[(w * 32 + i * 8) * 64]);
            gld16(bg[i] + kt, &Bs[(w * 32 + i * 8) * 64]);
        }
        asm volatile("s_waitcnt vmcnt(0)" ::: "memory");
        __syncthreads();
#pragma unroll
        for (int kk = 0; kk < 2; ++kk) {
            f16x8 af[4], bf[4];
            const int rsel  = lane & 15;
            const int slot0 = (lane >> 4) + kk * 4;
#pragma unroll
            for (int mi = 0; mi < 4; ++mi) {
                const int row = wm + mi * 16 + rsel;
                af[mi] = *reinterpret_cast<const f16x8*>(&As[row * 64 + swz8(row, slot0) * 8]);
            }
#pragma unroll
            for (int nj = 0; nj < 4; ++nj) {
                const int row = wn + nj * 16 + rsel;
                bf[nj] = *reinterpret_cast<const f16x8*>(&Bs[row * 64 + swz8(row, slot0) * 8]);
            }
            __builtin_amdgcn_s_setprio(1);
#pragma unroll
            for (int mi = 0; mi < 4; ++mi)
#pragma unroll
                for (int nj = 0; nj < 4; ++nj)
                    acc[mi][nj] = __builtin_amdgcn_mfma_f32_16x16x32_f16(af[mi], bf[nj], acc[mi][nj], 0, 0, 0);
            __builtin_amdgcn_s_setprio(0);
        }
        __syncthreads();
    }

    // epilogue: C/D layout col = lane&15, row = (lane>>4)*4 + j
    const int cl = lane & 15, g = lane >> 4;
#pragma unroll
    for (int mi = 0; mi < 4; ++mi) {
#pragma unroll
        for (int nj = 0; nj < 4; ++nj) {
            const int col = tn * 128 + wn + nj * 16 + cl;
            if (MODE == 1 && col >= DIMC) {
                // V chunk-tiled write: 4 consecutive kv at fixed d -> one 8B store
                const int gm0 = tm * 128 + wm + mi * 16 + g * 4;
                const int bb = gm0 / NKV;
                const int rr = gm0 - bb * NKV;
                const int vc = col - DIMC;
                f16x4 pk;
                pk[0] = (f16)acc[mi][nj][0]; pk[1] = (f16)acc[mi][nj][1];
                pk[2] = (f16)acc[mi][nj][2]; pk[3] = (f16)acc[mi][nj][3];
                *reinterpret_cast<f16x4*>(
                    Vt + ((((size_t)bb * 16 + (vc >> 6)) * NCHUNK + (rr >> 6)) * 64 + (vc & 63)) * 64 + (rr & 63)) = pk;
            } else {
#pragma unroll
                for (int j = 0; j < 4; ++j) {
                    const int gm = tm * 128 + wm + mi * 16 + g * 4 + j;
                    const float val = acc[mi][nj][j];
                    if (MODE == 0) {
                        const int bb = gm >> 11, rr = gm & 2047;
                        Cf16[(((size_t)bb * 16 + (col >> 6)) * NSEQ + rr) * 64 + (col & 63)] = (f16)val;
                    } else if (MODE == 1) {
                        const int bb = gm / NKV;
                        const int rr = gm - bb * NKV;
                        Cf16[(((size_t)bb * 16 + (col >> 6)) * NKV + rr) * 64 + (col & 63)] = (f16)val;
                    } else {
                        Cf32[(size_t)gm * DIMC + col] = val + bias[col];
                    }
                }
            }
        }
    }
}

// fused q + kv projection, XCD-slab swizzle: 1-D grid 1584 blocks.
// xcd = bid&7 owns g in [xcd*198, (xcd+1)*198): bx = g/24 spans ~8-9 consecutive
// A-panels (2.1-2.3 MB -> fits the XCD's private 4 MB L2) swept over all by.
__global__ __launch_bounds__(256, 3)
void gemm_qkv(const f16* __restrict__ xn, const f16* __restrict__ wqT,
              const f16* __restrict__ wkvT, const f16* __restrict__ mem16,
              f16* __restrict__ q16, f16* __restrict__ k16, f16* __restrict__ vt16)
{
    __shared__ __align__(16) f16 As[128 * 64];
    __shared__ __align__(16) f16 Bs[128 * 64];
    const int bid = blockIdx.x;
    const int g = (bid & 7) * 198 + (bid >> 3);   // bijective: [0,1584)
    const int by = g % 24;
    const int bx = g / 24;                        // 0..65
    if (by < 16) {
        gemm_body<1>(bx, by, As, Bs, xn, wkvT, mem16, k16, vt16, nullptr, nullptr);
    } else {
        if (bx >= 64) return;
        gemm_body<0>(bx, by - 16, As, Bs, xn, wqT, nullptr, q16, nullptr, nullptr, nullptr);
    }
}

// out proj, XCD-slab swizzle: 1-D grid 512. xcd owns bx in [xcd*8, xcd*8+8)
__global__ __launch_bounds__(256, 3)
void gemm_o(const f16* __restrict__ ao, const f16* __restrict__ woT,
            float* __restrict__ out, const float* __restrict__ bo)
{
    __shared__ __align__(16) f16 As[128 * 64];
    __shared__ __align__(16) f16 Bs[128 * 64];
    const int bid = blockIdx.x;
    const int g = (bid & 7) * 64 + (bid >> 3);    // bijective: [0,512)
    const int by = g & 7;
    const int bx = g >> 3;                        // 0..63
    gemm_body<2>(bx, by, As, Bs, ao, woT, nullptr, nullptr, nullptr, out, bo);
}

// ---------------- flash attention (r8/r11 known-good) ----------------
__global__ __launch_bounds__(512, 4)
void attn_kernel(const f16* __restrict__ q16, const f16* __restrict__ k16,
                 const f16* __restrict__ vt16, f16* __restrict__ ao16)
{
    __shared__ __align__(16) f16 Kb[3][64 * 64];
    __shared__ __align__(16) f16 Vb[3][64 * 64];

    const int raw = blockIdx.x;
    const int bh = (raw & 7) * 8 + ((raw >> 3) & 7);   // XCD co-location
    const int qt = raw >> 6;
    const int b = bh >> 4, h = bh & 15;
    const int tid = threadIdx.x, lane = tid & 63, w = tid >> 6;   // w = 0..7
    const int l31 = lane & 31, hi = lane >> 5;
    const int l3 = lane >> 3, l7 = lane & 7;
    const int gslot = (l7 ^ l3) * 8;

    const f16* kbase = k16  + (size_t)bh * NKV * 64;
    const f16* vbase = vt16 + (size_t)bh * NCHUNK * 4096;
    const f16* qbase = q16  + (size_t)bh * NSEQ * 64;

    const int srow = w * 8 + l3;
    const f16* kp = kbase + (size_t)srow * 64 + gslot;
    const f16* vp = vbase + (size_t)srow * 64 + gslot;

    f16x8 qf[4];
    {
        const int qrow = qt * 256 + w * 32 + l31;
#pragma unroll
        for (int ks = 0; ks < 4; ++ks)
            qf[ks] = *reinterpret_cast<const f16x8*>(
                qbase + (size_t)qrow * 64 + ks * 16 + hi * 8);
    }

    f32x16 Oa0 = {}, Oa1 = {};
    float lp0 = 0.0f, lp1 = 0.0f, lp2 = 0.0f, lp3 = 0.0f;

    f32x16 minus8;
#pragma unroll
    for (int r = 0; r < 16; ++r) minus8[r] = -8.0f;

#pragma unroll
    for (int c = 0; c < 2; ++c) {
        gld16(kp + (size_t)c * 4096, &Kb[c][w * 8 * 64]);
        gld16(vp + (size_t)c * 4096, &Vb[c][w * 8 * 64]);
    }

#if __has_builtin(__builtin_amdgcn_fdot2)
    const h16x2 ones = {(__fp16)1.0f, (__fp16)1.0f};
#endif

    int cur = 0, nxt = 2;
    for (int t = 0; t < NCHUNK; ++t) {
        if (t < NCHUNK - 1) asm volatile("s_waitcnt vmcnt(2)" ::: "memory");
        else                asm volatile("s_waitcnt vmcnt(0)" ::: "memory");
        __builtin_amdgcn_s_barrier();

        if (t + 2 < NCHUNK) {
            gld16(kp + (size_t)(t + 2) * 4096, &Kb[nxt][w * 8 * 64]);
            gld16(vp + (size_t)(t + 2) * 4096, &Vb[nxt][w * 8 * 64]);
        }
        const f16* Ks = Kb[cur];
        const f16* Vs = Vb[cur];

#pragma unroll
        for (int kb = 0; kb < 2; ++kb) {
            const int krow = kb * 32 + l31;
            f16x8 kf[4];
#pragma unroll
            for (int ks = 0; ks < 4; ++ks)
                kf[ks] = *reinterpret_cast<const f16x8*>(
                    &Ks[krow * 64 + ((2 * ks + hi) ^ (krow & 7)) * 8]);

            f32x16 sA;
            __builtin_amdgcn_s_setprio(1);
            sA = __builtin_amdgcn_mfma_f32_32x32x16_f16(kf[0], qf[0], minus8, 0, 0, 0);
#pragma unroll
            for (int ks = 1; ks < 4; ++ks)
                sA = __builtin_amdgcn_mfma_f32_32x32x16_f16(kf[ks], qf[ks], sA, 0, 0, 0);
            __builtin_amdgcn_s_setprio(0);

            float p[16];
#pragma unroll
            for (int r = 0; r < 16; ++r)
                p[r] = __builtin_amdgcn_exp2f(sA[r]);

            f16x8 pb[2];
#pragma unroll
            for (int s2 = 0; s2 < 2; ++s2) {
                u32 a  = pkrtz(p[s2 * 8 + 0], p[s2 * 8 + 1]);
                u32 b2 = pkrtz(p[s2 * 8 + 2], p[s2 * 8 + 3]);
                u32 c  = pkrtz(p[s2 * 8 + 4], p[s2 * 8 + 5]);
                u32 d  = pkrtz(p[s2 * 8 + 6], p[s2 * 8 + 7]);
                asm volatile("v_permlane32_swap_b32 %0, %1" : "+v"(a),  "+v"(c));
                asm volatile("v_permlane32_swap_b32 %0, %1" : "+v"(b2), "+v"(d));
#if __has_builtin(__builtin_amdgcn_fdot2)
                lp0 = __builtin_amdgcn_fdot2(__builtin_bit_cast(h16x2, a),  ones, lp0, false);
                lp1 = __builtin_amdgcn_fdot2(__builtin_bit_cast(h16x2, b2), ones, lp1, false);
                lp2 = __builtin_amdgcn_fdot2(__builtin_bit_cast(h16x2, c),  ones, lp2, false);
                lp3 = __builtin_amdgcn_fdot2(__builtin_bit_cast(h16x2, d),  ones, lp3, false);
#else
                {
                    h16x2 ha = __builtin_bit_cast(h16x2, a),  hb = __builtin_bit_cast(h16x2, b2);
                    h16x2 hc = __builtin_bit_cast(h16x2, c),  hd = __builtin_bit_cast(h16x2, d);
                    lp0 += (float)ha[0] + (float)ha[1];
                    lp1 += (float)hb[0] + (float)hb[1];
                    lp2 += (float)hc[0] + (float)hc[1];
                    lp3 += (float)hd[0] + (float)hd[1];
                }
#endif
                u32x4 wv = {a, b2, c, d};
                pb[s2] = __builtin_bit_cast(f16x8, wv);
            }

#pragma unroll
            for (int s2 = 0; s2 < 2; ++s2) {
                const int s = kb * 2 + s2;
                const int vr1 = 32 + l31;
                const f16x8 vf0 = *reinterpret_cast<const f16x8*>(
                    &Vs[l31 * 64 + ((2 * s + hi) ^ (l31 & 7)) * 8]);
                const f16x8 vf1 = *reinterpret_cast<const f16x8*>(
                    &Vs[vr1 * 64 + ((2 * s + hi) ^ (vr1 & 7)) * 8]);
                __builtin_amdgcn_s_setprio(1);
                Oa0 = __builtin_amdgcn_mfma_f32_32x32x16_f16(vf0, pb[s2], Oa0, 0, 0, 0);
                Oa1 = __builtin_amdgcn_mfma_f32_32x32x16_f16(vf1, pb[s2], Oa1, 0, 0, 0);
                __builtin_amdgcn_s_setprio(0);
            }
        }
        cur = (cur == 2) ? 0 : cur + 1;
        nxt = (nxt == 2) ? 0 : nxt + 1;
    }

    float l0 = (lp0 + lp1) + (lp2 + lp3);
    l0 += __shfl_xor(l0, 32, 64);
    const float rinv = 1.0f / l0;
    const int qrow = qt * 256 + w * 32 + l31;
#pragma unroll
    for (int rq = 0; rq < 4; ++rq) {
        const int d0 = rq * 8 + hi * 4;
        f16x4 pk;
        pk[0] = (f16)(Oa0[rq * 4 + 0] * rinv);
        pk[1] = (f16)(Oa0[rq * 4 + 1] * rinv);
        pk[2] = (f16)(Oa0[rq * 4 + 2] * rinv);
        pk[3] = (f16)(Oa0[rq * 4 + 3] * rinv);
        *reinterpret_cast<f16x4*>(
            ao16 + ((size_t)(b * NSEQ + qrow)) * DIMC + h * 64 + d0) = pk;
    }
#pragma unroll
    for (int rq = 0; rq < 4; ++rq) {
        const int d0 = 32 + rq * 8 + hi * 4;
        f16x4 pk;
        pk[0] = (f16)(Oa1[rq * 4 + 0] * rinv);
        pk[1] = (f16)(Oa1[rq * 4 + 1] * rinv);
        pk[2] = (f16)(Oa1[rq * 4 + 2] * rinv);
        pk[3] = (f16)(Oa1[rq * 4 + 3] * rinv);
        *reinterpret_cast<f16x4*>(
            ao16 + ((size_t)(b * NSEQ + qrow)) * DIMC + h * 64 + d0) = pk;
    }
}

// ---------------- launch ----------------
extern "C" void kernel_launch(void* const* d_in, const int* in_sizes, int n_in,
                              void* d_out, int out_size, void* d_ws, size_t ws_size,
                              hipStream_t stream)
{
    const float* x        = (const float*)d_in[0];
    const float* memories = (const float*)d_in[2];
    const float* ln_gamma = (const float*)d_in[3];
    const float* ln_beta  = (const float*)d_in[4];
    const float* Wq       = (const float*)d_in[5];
    const float* Wkv      = (const float*)d_in[6];
    const float* Wo       = (const float*)d_in[7];
    const float* bo       = (const float*)d_in[8];
    float* out = (float*)d_out;

    char* ws = (char*)d_ws;
    f16* xn16  = (f16*)(ws);                          // 16 MiB (reused as ao16)
    f16* q16   = (f16*)(ws + (16ull << 20));          // 16 MiB, head-major
    f16* k16   = (f16*)(ws + (32ull << 20));          // 16.5 MiB, head-major
    f16* vt16  = (f16*)(ws + (49ull << 20));          // 16.5 MiB, chunk-tiled
    f16* wqT   = (f16*)(ws + (66ull << 20));          // 2 MiB
    f16* wkvT  = (f16*)(ws + (68ull << 20));          // 4 MiB
    f16* woT   = (f16*)(ws + (72ull << 20));          // 2 MiB
    f16* mem16 = (f16*)(ws + (74ull << 20));          // 128 KiB
    f16* ao16  = xn16;   // xn16 dead after qkv GEMM

    // fused prep + LN: one launch (LN 2048 blocks + prep 6208 blocks)
    prep_ln_kernel<<<dim3(2048 + 6208), 256, 0, stream>>>(
        x, ln_gamma, ln_beta, Wq, Wkv, Wo, memories,
        xn16, wqT, wkvT, woT, mem16);

    // fused q & kv projections (XCD-slab swizzled grid)
    gemm_qkv<<<dim3(1584), 256, 0, stream>>>(xn16, wqT, wkvT, mem16, q16, k16, vt16);

    // attention -> ao16 (natural layout)
    attn_kernel<<<dim3(512), 512, 0, stream>>>(q16, k16, vt16, ao16);

    // out = ao @ Wo + bo (XCD-slab swizzled grid)
    gemm_o<<<dim3(512), 256, 0, stream>>>(ao16, woT, out, bo);

    (void)in_sizes; (void)n_in; (void)out_size; (void)ws_size;
}